// Round 7
// baseline (362.060 us; speedup 1.0000x reference)
//
#include <hip/hip_runtime.h>

// GINE 2-layer GNN: N=50000 nodes, E=800000 edges, d=128.
// Round 7: fuse aggregate+GEMM per 64-node bucket (one block = one bucket =
// one MFMA row-tile). Deletes aggb write+read (25.6MB/layer) and 2 launches.
// Aggregation phase keeps round-5 parallelism: 8 x 32-lane groups, 8-deep
// prefetch (round-4 lesson: never serialize the gather). bucket_csr now also
// sorts each node's edge list by src -> concurrent gathers cluster -> better
// per-XCD L2 hit rate. LDS pad 136->140 shorts (<=2-way bank alias on MFMA
// fragment reads). bf16 feature path (absmax 4.0 vs threshold 15.04).

typedef unsigned long long u64;
typedef unsigned int u32;
typedef unsigned short ushort;
typedef __attribute__((ext_vector_type(8))) short short8;
typedef __attribute__((ext_vector_type(4))) float f32x4;

constexpr int NN = 50000;
constexpr int NE = 800000;
constexpr int D  = 128;
constexpr int BSH = 6;                    // 64 nodes per bucket
constexpr int NB  = (NN + 63) >> BSH;     // 782 buckets
constexpr int NC  = 128;                  // edge chunks
constexpr int CHUNK = NE / NC;            // 6250
constexpr int BCAP = 4096;
constexpr int PAD = 140;                  // LDS row pitch in shorts

__device__ __forceinline__ ushort f2bf(float f) {
    u32 u = __float_as_uint(f);
    return (ushort)((u + 0x7FFFu + ((u >> 16) & 1u)) >> 16);
}
__device__ __forceinline__ u64 pack_edge(int src, int d6, float w) {
    return ((u64)__float_as_uint(w) << 32) | (u32)(src | (d6 << 17));
}

// ---------------- prep: casts ----------------

__global__ __launch_bounds__(256) void cast_x(
    const float* __restrict__ x, ushort* __restrict__ xb)
{
    int i = blockIdx.x * 256 + threadIdx.x;
    if (i >= NN * D / 8) return;
    int base = i * 8;
    float4 a = *(const float4*)(x + base);
    float4 b = *(const float4*)(x + base + 4);
    uint4 o;
    o.x = (u32)f2bf(a.x) | ((u32)f2bf(a.y) << 16);
    o.y = (u32)f2bf(a.z) | ((u32)f2bf(a.w) << 16);
    o.z = (u32)f2bf(b.x) | ((u32)f2bf(b.y) << 16);
    o.w = (u32)f2bf(b.z) | ((u32)f2bf(b.w) << 16);
    *(uint4*)(xb + base) = o;
}

__global__ __launch_bounds__(256) void prep_w(
    const float* __restrict__ W1, const float* __restrict__ W2,
    ushort* __restrict__ Wt1, ushort* __restrict__ Wt2)
{
    int b = blockIdx.x;
    const float* W  = (b >= 4) ? W2 : W1;
    ushort*      Wt = (b >= 4) ? Wt2 : Wt1;
    int k0 = (b & 3) * 32;
    for (int i = threadIdx.x; i < 32 * D; i += 256) {
        int n = i >> 5, r = i & 31;
        Wt[n * D + k0 + r] = f2bf(W[(k0 + r) * D + n]);
    }
}

// ---------------- bucket sort build ----------------

__global__ __launch_bounds__(256) void hist(
    const int* __restrict__ dst, int* __restrict__ G)
{
    __shared__ int hh[NB];
    int t = threadIdx.x, c = blockIdx.x;
    for (int i = t; i < NB; i += 256) hh[i] = 0;
    __syncthreads();
    int e0 = c * CHUNK;
    for (int i = t; i < CHUNK; i += 256)
        atomicAdd(&hh[dst[e0 + i] >> BSH], 1);
    __syncthreads();
    for (int i = t; i < NB; i += 256) G[c * NB + i] = hh[i];
}

__global__ __launch_bounds__(256) void colscan(
    const int* __restrict__ G, int* __restrict__ O, int* __restrict__ S)
{
    int b = blockIdx.x * 256 + threadIdx.x;
    if (b >= NB) return;
    int run = 0;
    #pragma unroll 16
    for (int c = 0; c < NC; ++c) {
        int g = G[c * NB + b];
        O[c * NB + b] = run;
        run += g;
    }
    S[b] = run;
}

__global__ __launch_bounds__(1024) void scanS(
    const int* __restrict__ S, int* __restrict__ B)
{
    __shared__ int s[1024];
    int t = threadIdx.x;
    int v = (t < NB) ? S[t] : 0;
    s[t] = v;
    __syncthreads();
    for (int d = 1; d < 1024; d <<= 1) {
        int u = (t >= d) ? s[t - d] : 0;
        __syncthreads();
        s[t] += u;
        __syncthreads();
    }
    if (t < NB) B[t] = s[t] - v;
    if (t == 0) B[NB] = NE;
}

__global__ __launch_bounds__(256) void bucket_scatter(
    const int*   __restrict__ src,
    const int*   __restrict__ dst,
    const float* __restrict__ ew,
    const int*   __restrict__ O,
    const int*   __restrict__ B,
    u64*         __restrict__ stage)
{
    __shared__ int base_s[NB];
    __shared__ int cnt_s[NB];
    int t = threadIdx.x, c = blockIdx.x;
    for (int i = t; i < NB; i += 256) {
        base_s[i] = B[i] + O[c * NB + i];
        cnt_s[i]  = 0;
    }
    __syncthreads();
    int e0 = c * CHUNK;
    for (int i = t; i < CHUNK; i += 256) {
        int e  = e0 + i;
        int d  = dst[e];
        int bk = d >> BSH;
        int r  = atomicAdd(&cnt_s[bk], 1);
        stage[base_s[bk] + r] = pack_edge(src[e], d & 63, ew[e]);
    }
}

// per bucket: counting sort by node, then per-node insertion sort by src,
// contiguous writeback, emit per-node CSR offsets.
__global__ __launch_bounds__(256) void bucket_csr(
    const int* __restrict__ B, u64* __restrict__ stage, int* __restrict__ off)
{
    __shared__ u64 buf[BCAP];           // 32 KB
    __shared__ int cnt[64];
    __shared__ int cur[64];
    __shared__ int noff[64];
    int t = threadIdx.x, b = blockIdx.x;
    int e0 = B[b], e1 = B[b + 1];
    int n = e1 - e0;
    if (n > BCAP) n = BCAP;
    if (t < 64) { cnt[t] = 0; cur[t] = 0; }
    __syncthreads();
    for (int i = t; i < n; i += 256)
        atomicAdd(&cnt[(int)((stage[e0 + i] >> 17) & 63)], 1);
    __syncthreads();
    if (t == 0) {
        int run = 0;
        for (int j = 0; j < 64; ++j) { noff[j] = run; run += cnt[j]; }
    }
    __syncthreads();
    int n0 = b << BSH;
    if (t < 64 && (n0 + t) < NN) off[n0 + t] = e0 + noff[t];
    if (b == NB - 1 && t == 0) off[NN] = NE;
    for (int i = t; i < n; i += 256) {
        u64 p = stage[e0 + i];
        int d6 = (int)((p >> 17) & 63);
        int r = atomicAdd(&cur[d6], 1);
        buf[noff[d6] + r] = p;
    }
    __syncthreads();
    if (t < 64) {                        // sort my node's sublist by src
        int s0 = noff[t], s1 = s0 + cnt[t];
        for (int i = s0 + 1; i < s1; ++i) {
            u64 key = buf[i];
            u32 ks = (u32)(key & 0x1FFFF);
            int j = i - 1;
            while (j >= s0 && ((u32)(buf[j] & 0x1FFFF)) > ks) {
                buf[j + 1] = buf[j]; --j;
            }
            buf[j + 1] = key;
        }
    }
    __syncthreads();
    for (int i = t; i < n; i += 256) stage[e0 + i] = buf[i];
}

// ---------- fused layer: A = h[bucket] + aggregate(bucket), out = A@W + b ----
// Block b = bucket b = rows [64b, 64b+64). Phase 1: 8 groups x 32 lanes,
// per-node 8-deep gather into f32 acc, +own h row, bf16 -> LDS As.
// Phase 2: round-6 MFMA tile (4 waves: 32-row x 64-col subtiles).

__global__ __launch_bounds__(256) void fused_layer(
    const ushort* __restrict__ hb,
    const int*    __restrict__ off,
    const u64*    __restrict__ stage,
    const float*  __restrict__ We,
    const float*  __restrict__ be,
    const ushort* __restrict__ Wtb,
    const float*  __restrict__ bias,
    ushort*       __restrict__ outb,   // layer 1 (or null)
    float*        __restrict__ outf,   // layer 2 (or null)
    int relu)
{
    __shared__ ushort As[64 * PAD];    // 17.5 KB
    __shared__ ushort Ws[D * PAD];     // 35 KB
    const int t = threadIdx.x, b = blockIdx.x;

    // stage W^T
    for (int c = t; c < D * (D / 4); c += 256) {
        int r = c >> 5, k4 = (c & 31) << 2;
        *(uint2*)&Ws[r * PAD + k4] = *(const uint2*)(Wtb + r * D + k4);
    }

    // phase 1: aggregation
    const int g = t >> 5, l = t & 31, d4 = l << 2;
    const float4 wv = *(const float4*)(We + d4);
    const float4 bv = *(const float4*)(be + d4);

    for (int nl = g; nl < 64; nl += 8) {
        int nd = (b << BSH) + nl;
        float ax = 0.f, ay = 0.f, az = 0.f, aw = 0.f;
        if (nd < NN) {
            int e0 = off[nd], e1 = off[nd + 1];
            for (int e = e0; e < e1; e += 8) {
                int m = e1 - e; if (m > 8) m = 8;
                u64 p[8];
                #pragma unroll
                for (int k = 0; k < 8; ++k) p[k] = (k < m) ? stage[e + k] : 0;
                uint2 hv[8];
                #pragma unroll
                for (int k = 0; k < 8; ++k)
                    hv[k] = *(const uint2*)(hb + (size_t)(p[k] & 0x1FFFF) * D + d4);
                #pragma unroll
                for (int k = 0; k < 8; ++k) {
                    if (k < m) {
                        float w = __uint_as_float((u32)(p[k] >> 32));
                        float hx = __uint_as_float((hv[k].x & 0xFFFFu) << 16);
                        float hy = __uint_as_float(hv[k].x & 0xFFFF0000u);
                        float hz = __uint_as_float((hv[k].y & 0xFFFFu) << 16);
                        float hw = __uint_as_float(hv[k].y & 0xFFFF0000u);
                        ax += fmaxf(0.f, hx + fmaf(w, wv.x, bv.x));
                        ay += fmaxf(0.f, hy + fmaf(w, wv.y, bv.y));
                        az += fmaxf(0.f, hz + fmaf(w, wv.z, bv.z));
                        aw += fmaxf(0.f, hw + fmaf(w, wv.w, bv.w));
                    }
                }
            }
            uint2 u = *(const uint2*)(hb + (size_t)nd * D + d4);   // (1+eps)*x, eps=0
            ax += __uint_as_float((u.x & 0xFFFFu) << 16);
            ay += __uint_as_float(u.x & 0xFFFF0000u);
            az += __uint_as_float((u.y & 0xFFFFu) << 16);
            aw += __uint_as_float(u.y & 0xFFFF0000u);
        }
        uint2 o;
        o.x = (u32)f2bf(ax) | ((u32)f2bf(ay) << 16);
        o.y = (u32)f2bf(az) | ((u32)f2bf(aw) << 16);
        *(uint2*)&As[nl * PAD + d4] = o;
    }
    __syncthreads();

    // phase 2: MFMA
    const int wave = t >> 6;
    const int lane = t & 63;
    const int q    = lane >> 4;
    const int m    = lane & 15;
    const int wr   = (wave >> 1) * 32;
    const int wc   = (wave & 1) * 64;

    f32x4 acc[2][4] = {};
    #pragma unroll
    for (int kb = 0; kb < 4; ++kb) {
        int ak = kb * 32 + q * 8;
        short8 af[2];
        #pragma unroll
        for (int rg = 0; rg < 2; ++rg)
            af[rg] = *(const short8*)&As[(wr + rg * 16 + m) * PAD + ak];
        #pragma unroll
        for (int ct = 0; ct < 4; ++ct) {
            short8 bf = *(const short8*)&Ws[(wc + ct * 16 + m) * PAD + ak];
            #pragma unroll
            for (int rg = 0; rg < 2; ++rg)
                acc[rg][ct] = __builtin_amdgcn_mfma_f32_16x16x32_bf16(
                    af[rg], bf, acc[rg][ct], 0, 0, 0);
        }
    }

    const int row0 = b << BSH;
    #pragma unroll
    for (int ct = 0; ct < 4; ++ct) {
        int col = wc + ct * 16 + m;
        float bc = bias[col];
        #pragma unroll
        for (int rg = 0; rg < 2; ++rg) {
            #pragma unroll
            for (int r = 0; r < 4; ++r) {
                int grow = row0 + wr + rg * 16 + q * 4 + r;
                if (grow < NN) {
                    float v = acc[rg][ct][r] + bc;
                    if (relu) v = fmaxf(0.f, v);
                    if (outb) outb[(size_t)grow * D + col] = f2bf(v);
                    else      outf[(size_t)grow * D + col] = v;
                }
            }
        }
    }
}

extern "C" void kernel_launch(void* const* d_in, const int* in_sizes, int n_in,
                              void* d_out, int out_size, void* d_ws, size_t ws_size,
                              hipStream_t stream)
{
    const float* x   = (const float*)d_in[0];
    const int*   ei  = (const int*)  d_in[1];
    const float* ew  = (const float*)d_in[2];
    const float* We1 = (const float*)d_in[3];
    const float* be1 = (const float*)d_in[4];
    const float* W1  = (const float*)d_in[5];
    const float* b1  = (const float*)d_in[6];
    const float* We2 = (const float*)d_in[7];
    const float* be2 = (const float*)d_in[8];
    const float* W2  = (const float*)d_in[9];
    const float* b2  = (const float*)d_in[10];

    float* out = (float*)d_out;

    // workspace (~33 MB)
    ushort* xb   = (ushort*)d_ws;                    // NN*D bf16
    ushort* hb   = xb + (size_t)NN * D;              // NN*D
    ushort* Wt1  = hb + (size_t)NN * D;              // 16384
    ushort* Wt2  = Wt1 + D * D;                      // 16384
    u64*   stage = (u64*)(Wt2 + D * D);              // NE u64
    int*   G     = (int*)(stage + NE);               // NC*NB
    int*   O     = G + NC * NB;                      // NC*NB
    int*   S     = O + NC * NB;                      // NB
    int*   B     = S + NB;                           // NB+1
    int*   off   = B + NB + 1;                       // NN+1

    const int* src = ei;
    const int* dst = ei + NE;

    dim3 cgrid((NN * D / 8 + 255) / 256);

    // ---- prep ----
    cast_x<<<cgrid, 256, 0, stream>>>(x, xb);
    prep_w<<<8, 256, 0, stream>>>(W1, W2, Wt1, Wt2);

    // ---- bucket-sorted CSR build ----
    hist<<<NC, 256, 0, stream>>>(dst, G);
    colscan<<<(NB + 255) / 256, 256, 0, stream>>>(G, O, S);
    scanS<<<1, 1024, 0, stream>>>(S, B);
    bucket_scatter<<<NC, 256, 0, stream>>>(src, dst, ew, O, B, stage);
    bucket_csr<<<NB, 256, 0, stream>>>(B, stage, off);

    // ---- layer 1 (out: hb bf16) ----
    fused_layer<<<NB, 256, 0, stream>>>(xb, off, stage, We1, be1, Wt1, b1,
                                        hb, nullptr, 1);
    // ---- layer 2 (out: f32) ----
    fused_layer<<<NB, 256, 0, stream>>>(hb, off, stage, We2, be2, Wt2, b2,
                                        nullptr, out, 0);
}

// Round 8
// 328.109 us; speedup vs baseline: 1.1035x; 1.1035x over previous
//
#include <hip/hip_runtime.h>

// GINE 2-layer GNN: N=50000 nodes, E=800000 edges, d=128.
// Round 8: revert round-7 fusion (92us @ 17.8% occupancy: 53.7KB LDS capped
// 3 blocks/CU and coupled the latency-bound gather to the MFMA phase ->
// 1.18 TB/s vs 3.6 TB/s split). Keep the split round-6 structure plus:
//  - bucket_csr sorts each node's edge list by src (better gather L2 locality)
//  - cast_x + prep_w merged into one prep kernel (-1 launch)
//  - nontemporal stores for aggb + final out (don't evict gather-hot h from
//    L2); nontemporal load of aggb in the GEMM (read-once stream).
// bf16 feature path, f32 accumulation (absmax 4.0 vs threshold 15.04).

typedef unsigned long long u64;
typedef unsigned int u32;
typedef unsigned short ushort;
typedef __attribute__((ext_vector_type(8))) short short8;
typedef __attribute__((ext_vector_type(4))) float f32x4;

constexpr int NN = 50000;
constexpr int NE = 800000;
constexpr int D  = 128;
constexpr int BSH = 6;                    // 64 nodes per bucket
constexpr int NB  = (NN + 63) >> BSH;     // 782 buckets
constexpr int NC  = 128;                  // edge chunks
constexpr int CHUNK = NE / NC;            // 6250
constexpr int BCAP = 4096;
constexpr int GR = 64;                    // GEMM rows per block
constexpr int GG = (NN + GR - 1) / GR;    // 782
constexpr int CBLK = NN * D / 8 / 256;    // 3125 cast blocks (exact)

__device__ __forceinline__ ushort f2bf(float f) {
    u32 u = __float_as_uint(f);
    return (ushort)((u + 0x7FFFu + ((u >> 16) & 1u)) >> 16);
}
__device__ __forceinline__ u64 pack_edge(int src, int d6, float w) {
    return ((u64)__float_as_uint(w) << 32) | (u32)(src | (d6 << 17));
}

// ---------------- prep: cast x -> bf16, transpose+cast W1/W2 ----------------

__global__ __launch_bounds__(256) void prep(
    const float* __restrict__ x,  ushort* __restrict__ xb,
    const float* __restrict__ W1, const float* __restrict__ W2,
    ushort* __restrict__ Wt1, ushort* __restrict__ Wt2)
{
    int blk = blockIdx.x;
    if (blk < CBLK) {
        int base = (blk * 256 + threadIdx.x) * 8;
        float4 a = *(const float4*)(x + base);
        float4 b = *(const float4*)(x + base + 4);
        uint4 o;
        o.x = (u32)f2bf(a.x) | ((u32)f2bf(a.y) << 16);
        o.y = (u32)f2bf(a.z) | ((u32)f2bf(a.w) << 16);
        o.z = (u32)f2bf(b.x) | ((u32)f2bf(b.y) << 16);
        o.w = (u32)f2bf(b.z) | ((u32)f2bf(b.w) << 16);
        *(uint4*)(xb + base) = o;
    } else {
        int b = blk - CBLK;                 // 0..7
        const float* W  = (b >= 4) ? W2 : W1;
        ushort*      Wt = (b >= 4) ? Wt2 : Wt1;
        int k0 = (b & 3) * 32;
        for (int i = threadIdx.x; i < 32 * D; i += 256) {
            int n = i >> 5, r = i & 31;
            Wt[n * D + k0 + r] = f2bf(W[(k0 + r) * D + n]);
        }
    }
}

// ---------------- bucket sort build ----------------

__global__ __launch_bounds__(256) void hist(
    const int* __restrict__ dst, int* __restrict__ G)
{
    __shared__ int hh[NB];
    int t = threadIdx.x, c = blockIdx.x;
    for (int i = t; i < NB; i += 256) hh[i] = 0;
    __syncthreads();
    int e0 = c * CHUNK;
    for (int i = t; i < CHUNK; i += 256)
        atomicAdd(&hh[dst[e0 + i] >> BSH], 1);
    __syncthreads();
    for (int i = t; i < NB; i += 256) G[c * NB + i] = hh[i];
}

__global__ __launch_bounds__(256) void colscan(
    const int* __restrict__ G, int* __restrict__ O, int* __restrict__ S)
{
    int b = blockIdx.x * 256 + threadIdx.x;
    if (b >= NB) return;
    int run = 0;
    #pragma unroll 16
    for (int c = 0; c < NC; ++c) {
        int g = G[c * NB + b];
        O[c * NB + b] = run;
        run += g;
    }
    S[b] = run;
}

__global__ __launch_bounds__(1024) void scanS(
    const int* __restrict__ S, int* __restrict__ B)
{
    __shared__ int s[1024];
    int t = threadIdx.x;
    int v = (t < NB) ? S[t] : 0;
    s[t] = v;
    __syncthreads();
    for (int d = 1; d < 1024; d <<= 1) {
        int u = (t >= d) ? s[t - d] : 0;
        __syncthreads();
        s[t] += u;
        __syncthreads();
    }
    if (t < NB) B[t] = s[t] - v;
    if (t == 0) B[NB] = NE;
}

__global__ __launch_bounds__(256) void bucket_scatter(
    const int*   __restrict__ src,
    const int*   __restrict__ dst,
    const float* __restrict__ ew,
    const int*   __restrict__ O,
    const int*   __restrict__ B,
    u64*         __restrict__ stage)
{
    __shared__ int base_s[NB];
    __shared__ int cnt_s[NB];
    int t = threadIdx.x, c = blockIdx.x;
    for (int i = t; i < NB; i += 256) {
        base_s[i] = B[i] + O[c * NB + i];
        cnt_s[i]  = 0;
    }
    __syncthreads();
    int e0 = c * CHUNK;
    for (int i = t; i < CHUNK; i += 256) {
        int e  = e0 + i;
        int d  = dst[e];
        int bk = d >> BSH;
        int r  = atomicAdd(&cnt_s[bk], 1);
        stage[base_s[bk] + r] = pack_edge(src[e], d & 63, ew[e]);
    }
}

// per bucket: counting sort by node, per-node insertion sort by src,
// contiguous writeback, emit per-node CSR offsets.
__global__ __launch_bounds__(256) void bucket_csr(
    const int* __restrict__ B, u64* __restrict__ stage, int* __restrict__ off)
{
    __shared__ u64 buf[BCAP];           // 32 KB
    __shared__ int cnt[64];
    __shared__ int cur[64];
    __shared__ int noff[64];
    int t = threadIdx.x, b = blockIdx.x;
    int e0 = B[b], e1 = B[b + 1];
    int n = e1 - e0;
    if (n > BCAP) n = BCAP;
    if (t < 64) { cnt[t] = 0; cur[t] = 0; }
    __syncthreads();
    for (int i = t; i < n; i += 256)
        atomicAdd(&cnt[(int)((stage[e0 + i] >> 17) & 63)], 1);
    __syncthreads();
    if (t == 0) {
        int run = 0;
        for (int j = 0; j < 64; ++j) { noff[j] = run; run += cnt[j]; }
    }
    __syncthreads();
    int n0 = b << BSH;
    if (t < 64 && (n0 + t) < NN) off[n0 + t] = e0 + noff[t];
    if (b == NB - 1 && t == 0) off[NN] = NE;
    for (int i = t; i < n; i += 256) {
        u64 p = stage[e0 + i];
        int d6 = (int)((p >> 17) & 63);
        int r = atomicAdd(&cur[d6], 1);
        buf[noff[d6] + r] = p;
    }
    __syncthreads();
    if (t < 64) {                        // sort my node's sublist by src
        int s0 = noff[t], s1 = s0 + cnt[t];
        for (int i = s0 + 1; i < s1; ++i) {
            u64 key = buf[i];
            u32 ks = (u32)(key & 0x1FFFF);
            int j = i - 1;
            while (j >= s0 && ((u32)(buf[j] & 0x1FFFF)) > ks) {
                buf[j + 1] = buf[j]; --j;
            }
            buf[j + 1] = key;
        }
    }
    __syncthreads();
    for (int i = t; i < n; i += 256) stage[e0 + i] = buf[i];
}

// ------------- per-layer aggregate (bf16 gather, 8-deep, f32 accum) -------

__global__ __launch_bounds__(256) void aggregate(
    const ushort* __restrict__ hb,
    const int*    __restrict__ off,
    const u64*    __restrict__ epk,
    const float*  __restrict__ We,
    const float*  __restrict__ be,
    ushort*       __restrict__ aggb)
{
    int tid = blockIdx.x * 256 + threadIdx.x;
    int n = tid >> 5;
    if (n >= NN) return;
    int d4 = (tid & 31) << 2;

    float4 wv = *(const float4*)(We + d4);
    float4 bv = *(const float4*)(be + d4);

    int e0 = off[n], e1 = off[n + 1];
    float ax = 0.f, ay = 0.f, az = 0.f, aw = 0.f;

    for (int e = e0; e < e1; e += 8) {
        int m = e1 - e; if (m > 8) m = 8;
        u64 p[8];
        #pragma unroll
        for (int k = 0; k < 8; ++k) p[k] = (k < m) ? epk[e + k] : 0;
        uint2 hv[8];
        #pragma unroll
        for (int k = 0; k < 8; ++k) {
            int s = (int)(p[k] & 0x1FFFF);
            hv[k] = *(const uint2*)(hb + (size_t)s * D + d4);  // 8 in flight
        }
        #pragma unroll
        for (int k = 0; k < 8; ++k) {
            if (k < m) {
                float w = __uint_as_float((u32)(p[k] >> 32));
                float hx = __uint_as_float((hv[k].x & 0xFFFFu) << 16);
                float hy = __uint_as_float(hv[k].x & 0xFFFF0000u);
                float hz = __uint_as_float((hv[k].y & 0xFFFFu) << 16);
                float hw = __uint_as_float(hv[k].y & 0xFFFF0000u);
                ax += fmaxf(0.f, hx + fmaf(w, wv.x, bv.x));
                ay += fmaxf(0.f, hy + fmaf(w, wv.y, bv.y));
                az += fmaxf(0.f, hz + fmaf(w, wv.z, bv.z));
                aw += fmaxf(0.f, hw + fmaf(w, wv.w, bv.w));
            }
        }
    }
    u64 o = (u64)((u32)f2bf(ax) | ((u32)f2bf(ay) << 16))
          | ((u64)((u32)f2bf(az) | ((u32)f2bf(aw) << 16)) << 32);
    __builtin_nontemporal_store(o, (u64*)(aggb + (size_t)n * D + d4));
}

// ---------- MFMA GEMM: out = (relu?)((A1+A2) @ W + bias) ----------

__global__ __launch_bounds__(256) void gemm_mfma(
    const ushort* __restrict__ A1b,
    const ushort* __restrict__ A2b,   // aggb (streamed, read-once)
    const ushort* __restrict__ Wtb,
    const float*  __restrict__ bias,
    float*        __restrict__ outf,   // layer 2 (or null)
    ushort*       __restrict__ outb,   // layer 1 (or null)
    int relu)
{
    __shared__ ushort As[GR * 140];
    __shared__ ushort Ws[D * 140];

    const int t    = threadIdx.x;
    const int row0 = blockIdx.x * GR;

    for (int c = t; c < GR * (D / 4); c += 256) {
        int r  = c >> 5;
        int k4 = (c & 31) << 2;
        int row = row0 + r;
        uint2 o = make_uint2(0u, 0u);
        if (row < NN) {
            uint2 u1 = *(const uint2*)(A1b + (size_t)row * D + k4);
            u64 uu = __builtin_nontemporal_load((const u64*)(A2b + (size_t)row * D + k4));
            uint2 u2 = make_uint2((u32)uu, (u32)(uu >> 32));
            float s0 = __uint_as_float((u1.x & 0xFFFFu) << 16) + __uint_as_float((u2.x & 0xFFFFu) << 16);
            float s1 = __uint_as_float(u1.x & 0xFFFF0000u)     + __uint_as_float(u2.x & 0xFFFF0000u);
            float s2 = __uint_as_float((u1.y & 0xFFFFu) << 16) + __uint_as_float((u2.y & 0xFFFFu) << 16);
            float s3 = __uint_as_float(u1.y & 0xFFFF0000u)     + __uint_as_float(u2.y & 0xFFFF0000u);
            o.x = (u32)f2bf(s0) | ((u32)f2bf(s1) << 16);
            o.y = (u32)f2bf(s2) | ((u32)f2bf(s3) << 16);
        }
        *(uint2*)&As[r * 140 + k4] = o;
    }
    for (int c = t; c < D * (D / 4); c += 256) {
        int r  = c >> 5;
        int k4 = (c & 31) << 2;
        *(uint2*)&Ws[r * 140 + k4] = *(const uint2*)(Wtb + r * D + k4);
    }
    __syncthreads();

    const int wave = t >> 6;
    const int lane = t & 63;
    const int q    = lane >> 4;
    const int m    = lane & 15;
    const int wr   = (wave >> 1) * 32;
    const int wc   = (wave & 1) * 64;

    f32x4 acc[2][4] = {};
    #pragma unroll
    for (int kb = 0; kb < 4; ++kb) {
        int ak = kb * 32 + q * 8;
        short8 af[2];
        #pragma unroll
        for (int rg = 0; rg < 2; ++rg)
            af[rg] = *(const short8*)&As[(wr + rg * 16 + m) * 140 + ak];
        #pragma unroll
        for (int ct = 0; ct < 4; ++ct) {
            short8 bf = *(const short8*)&Ws[(wc + ct * 16 + m) * 140 + ak];
            #pragma unroll
            for (int rg = 0; rg < 2; ++rg)
                acc[rg][ct] = __builtin_amdgcn_mfma_f32_16x16x32_bf16(
                    af[rg], bf, acc[rg][ct], 0, 0, 0);
        }
    }

    #pragma unroll
    for (int ct = 0; ct < 4; ++ct) {
        int col = wc + ct * 16 + m;
        float bc = bias[col];
        #pragma unroll
        for (int rg = 0; rg < 2; ++rg) {
            #pragma unroll
            for (int r = 0; r < 4; ++r) {
                int grow = row0 + wr + rg * 16 + q * 4 + r;
                if (grow < NN) {
                    float v = acc[rg][ct][r] + bc;
                    if (relu) v = fmaxf(0.f, v);
                    if (outb) outb[(size_t)grow * D + col] = f2bf(v);
                    else __builtin_nontemporal_store(v, outf + (size_t)grow * D + col);
                }
            }
        }
    }
}

extern "C" void kernel_launch(void* const* d_in, const int* in_sizes, int n_in,
                              void* d_out, int out_size, void* d_ws, size_t ws_size,
                              hipStream_t stream)
{
    const float* x   = (const float*)d_in[0];
    const int*   ei  = (const int*)  d_in[1];
    const float* ew  = (const float*)d_in[2];
    const float* We1 = (const float*)d_in[3];
    const float* be1 = (const float*)d_in[4];
    const float* W1  = (const float*)d_in[5];
    const float* b1  = (const float*)d_in[6];
    const float* We2 = (const float*)d_in[7];
    const float* be2 = (const float*)d_in[8];
    const float* W2  = (const float*)d_in[9];
    const float* b2  = (const float*)d_in[10];

    float* out = (float*)d_out;

    // workspace (~46 MB)
    ushort* xb   = (ushort*)d_ws;                    // NN*D bf16
    ushort* hb   = xb + (size_t)NN * D;              // NN*D
    ushort* aggb = hb + (size_t)NN * D;              // NN*D
    ushort* Wt1  = aggb + (size_t)NN * D;            // 16384
    ushort* Wt2  = Wt1 + D * D;                      // 16384
    u64*   stage = (u64*)(Wt2 + D * D);              // NE u64
    int*   G     = (int*)(stage + NE);               // NC*NB
    int*   O     = G + NC * NB;                      // NC*NB
    int*   S     = O + NC * NB;                      // NB
    int*   B     = S + NB;                           // NB+1
    int*   off   = B + NB + 1;                       // NN+1

    const int* src = ei;
    const int* dst = ei + NE;

    dim3 agrid((NN * 32 + 255) / 256);               // 6250

    // ---- prep (cast x + transpose W) ----
    prep<<<CBLK + 8, 256, 0, stream>>>(x, xb, W1, W2, Wt1, Wt2);

    // ---- bucket-sorted CSR build ----
    hist<<<NC, 256, 0, stream>>>(dst, G);
    colscan<<<(NB + 255) / 256, 256, 0, stream>>>(G, O, S);
    scanS<<<1, 1024, 0, stream>>>(S, B);
    bucket_scatter<<<NC, 256, 0, stream>>>(src, dst, ew, O, B, stage);
    bucket_csr<<<NB, 256, 0, stream>>>(B, stage, off);

    // ---- layer 1 ----
    aggregate<<<agrid, 256, 0, stream>>>(xb, off, stage, We1, be1, aggb);
    gemm_mfma<<<GG, 256, 0, stream>>>(xb, aggb, Wt1, b1, nullptr, hb, 1);

    // ---- layer 2 ----
    aggregate<<<agrid, 256, 0, stream>>>(hb, off, stage, We2, be2, aggb);
    gemm_mfma<<<GG, 256, 0, stream>>>(hb, aggb, Wt2, b2, out, nullptr, 0);
}

// Round 9
// 274.795 us; speedup vs baseline: 1.3176x; 1.1940x over previous
//
#include <hip/hip_runtime.h>

// GINE 2-layer GNN: N=50000 nodes, E=800000 edges, d=128.
// Round 9: round-6 structure (281us) + round-8 keepers, minus the regression.
//  - REMOVED the per-node insertion sort in bucket_csr (round 8: 51us, 1.07M
//    LDS bank conflicts, 64/256 threads divergent-serial -> +40us net loss).
//  - prep (cast x, transpose W) and hist fused into one kernel (disjoint
//    block ranges, independent data) -> one fewer launch.
//  - nontemporal stores for aggb/final out, nontemporal load of aggb (kept).
// bf16 feature path, f32 accumulation (absmax 4.0 vs threshold 15.04).

typedef unsigned long long u64;
typedef unsigned int u32;
typedef unsigned short ushort;
typedef __attribute__((ext_vector_type(8))) short short8;
typedef __attribute__((ext_vector_type(4))) float f32x4;

constexpr int NN = 50000;
constexpr int NE = 800000;
constexpr int D  = 128;
constexpr int BSH = 6;                    // 64 nodes per bucket
constexpr int NB  = (NN + 63) >> BSH;     // 782 buckets
constexpr int NC  = 128;                  // edge chunks
constexpr int CHUNK = NE / NC;            // 6250
constexpr int BCAP = 4096;
constexpr int GR = 64;                    // GEMM rows per block
constexpr int GG = (NN + GR - 1) / GR;    // 782
constexpr int CBLK = NN * D / 8 / 256;    // 3125 cast blocks (exact)

__device__ __forceinline__ ushort f2bf(float f) {
    u32 u = __float_as_uint(f);
    return (ushort)((u + 0x7FFFu + ((u >> 16) & 1u)) >> 16);
}
__device__ __forceinline__ u64 pack_edge(int src, int d6, float w) {
    return ((u64)__float_as_uint(w) << 32) | (u32)(src | (d6 << 17));
}

// ---- prep+hist: cast x -> bf16, transpose+cast W1/W2, dst histogram ----
// blocks [0,CBLK): cast; [CBLK,CBLK+8): W transpose; [CBLK+8,CBLK+8+NC): hist.

__global__ __launch_bounds__(256) void prep_hist(
    const float* __restrict__ x,  ushort* __restrict__ xb,
    const float* __restrict__ W1, const float* __restrict__ W2,
    ushort* __restrict__ Wt1, ushort* __restrict__ Wt2,
    const int* __restrict__ dst, int* __restrict__ G)
{
    int blk = blockIdx.x;
    if (blk < CBLK) {
        int base = (blk * 256 + threadIdx.x) * 8;
        float4 a = *(const float4*)(x + base);
        float4 b = *(const float4*)(x + base + 4);
        uint4 o;
        o.x = (u32)f2bf(a.x) | ((u32)f2bf(a.y) << 16);
        o.y = (u32)f2bf(a.z) | ((u32)f2bf(a.w) << 16);
        o.z = (u32)f2bf(b.x) | ((u32)f2bf(b.y) << 16);
        o.w = (u32)f2bf(b.z) | ((u32)f2bf(b.w) << 16);
        *(uint4*)(xb + base) = o;
    } else if (blk < CBLK + 8) {
        int b = blk - CBLK;                 // 0..7
        const float* W  = (b >= 4) ? W2 : W1;
        ushort*      Wt = (b >= 4) ? Wt2 : Wt1;
        int k0 = (b & 3) * 32;
        for (int i = threadIdx.x; i < 32 * D; i += 256) {
            int n = i >> 5, r = i & 31;
            Wt[n * D + k0 + r] = f2bf(W[(k0 + r) * D + n]);
        }
    } else {
        __shared__ int hh[NB];
        int t = threadIdx.x, c = blk - CBLK - 8;
        for (int i = t; i < NB; i += 256) hh[i] = 0;
        __syncthreads();
        int e0 = c * CHUNK;
        for (int i = t; i < CHUNK; i += 256)
            atomicAdd(&hh[dst[e0 + i] >> BSH], 1);
        __syncthreads();
        for (int i = t; i < NB; i += 256) G[c * NB + i] = hh[i];
    }
}

// ---------------- bucket sort build ----------------

__global__ __launch_bounds__(256) void colscan(
    const int* __restrict__ G, int* __restrict__ O, int* __restrict__ S)
{
    int b = blockIdx.x * 256 + threadIdx.x;
    if (b >= NB) return;
    int run = 0;
    #pragma unroll 16
    for (int c = 0; c < NC; ++c) {
        int g = G[c * NB + b];
        O[c * NB + b] = run;
        run += g;
    }
    S[b] = run;
}

__global__ __launch_bounds__(1024) void scanS(
    const int* __restrict__ S, int* __restrict__ B)
{
    __shared__ int s[1024];
    int t = threadIdx.x;
    int v = (t < NB) ? S[t] : 0;
    s[t] = v;
    __syncthreads();
    for (int d = 1; d < 1024; d <<= 1) {
        int u = (t >= d) ? s[t - d] : 0;
        __syncthreads();
        s[t] += u;
        __syncthreads();
    }
    if (t < NB) B[t] = s[t] - v;
    if (t == 0) B[NB] = NE;
}

__global__ __launch_bounds__(256) void bucket_scatter(
    const int*   __restrict__ src,
    const int*   __restrict__ dst,
    const float* __restrict__ ew,
    const int*   __restrict__ O,
    const int*   __restrict__ B,
    u64*         __restrict__ stage)
{
    __shared__ int base_s[NB];
    __shared__ int cnt_s[NB];
    int t = threadIdx.x, c = blockIdx.x;
    for (int i = t; i < NB; i += 256) {
        base_s[i] = B[i] + O[c * NB + i];
        cnt_s[i]  = 0;
    }
    __syncthreads();
    int e0 = c * CHUNK;
    for (int i = t; i < CHUNK; i += 256) {
        int e  = e0 + i;
        int d  = dst[e];
        int bk = d >> BSH;
        int r  = atomicAdd(&cnt_s[bk], 1);
        stage[base_s[bk] + r] = pack_edge(src[e], d & 63, ew[e]);
    }
}

// per bucket: counting sort by node, contiguous writeback, per-node offsets.
__global__ __launch_bounds__(256) void bucket_csr(
    const int* __restrict__ B, u64* __restrict__ stage, int* __restrict__ off)
{
    __shared__ u64 buf[BCAP];           // 32 KB
    __shared__ int cnt[64];
    __shared__ int cur[64];
    __shared__ int noff[64];
    int t = threadIdx.x, b = blockIdx.x;
    int e0 = B[b], e1 = B[b + 1];
    int n = e1 - e0;
    if (n > BCAP) n = BCAP;
    if (t < 64) { cnt[t] = 0; cur[t] = 0; }
    __syncthreads();
    for (int i = t; i < n; i += 256)
        atomicAdd(&cnt[(int)((stage[e0 + i] >> 17) & 63)], 1);
    __syncthreads();
    if (t == 0) {
        int run = 0;
        for (int j = 0; j < 64; ++j) { noff[j] = run; run += cnt[j]; }
    }
    __syncthreads();
    int n0 = b << BSH;
    if (t < 64 && (n0 + t) < NN) off[n0 + t] = e0 + noff[t];
    if (b == NB - 1 && t == 0) off[NN] = NE;
    for (int i = t; i < n; i += 256) {
        u64 p = stage[e0 + i];
        int d6 = (int)((p >> 17) & 63);
        int r = atomicAdd(&cur[d6], 1);
        buf[noff[d6] + r] = p;
    }
    __syncthreads();
    for (int i = t; i < n; i += 256) stage[e0 + i] = buf[i];
}

// ------------- per-layer aggregate (bf16 gather, 8-deep, f32 accum) -------

__global__ __launch_bounds__(256) void aggregate(
    const ushort* __restrict__ hb,
    const int*    __restrict__ off,
    const u64*    __restrict__ epk,
    const float*  __restrict__ We,
    const float*  __restrict__ be,
    ushort*       __restrict__ aggb)
{
    int tid = blockIdx.x * 256 + threadIdx.x;
    int n = tid >> 5;
    if (n >= NN) return;
    int d4 = (tid & 31) << 2;

    float4 wv = *(const float4*)(We + d4);
    float4 bv = *(const float4*)(be + d4);

    int e0 = off[n], e1 = off[n + 1];
    float ax = 0.f, ay = 0.f, az = 0.f, aw = 0.f;

    for (int e = e0; e < e1; e += 8) {
        int m = e1 - e; if (m > 8) m = 8;
        u64 p[8];
        #pragma unroll
        for (int k = 0; k < 8; ++k) p[k] = (k < m) ? epk[e + k] : 0;
        uint2 hv[8];
        #pragma unroll
        for (int k = 0; k < 8; ++k) {
            int s = (int)(p[k] & 0x1FFFF);
            hv[k] = *(const uint2*)(hb + (size_t)s * D + d4);  // 8 in flight
        }
        #pragma unroll
        for (int k = 0; k < 8; ++k) {
            if (k < m) {
                float w = __uint_as_float((u32)(p[k] >> 32));
                float hx = __uint_as_float((hv[k].x & 0xFFFFu) << 16);
                float hy = __uint_as_float(hv[k].x & 0xFFFF0000u);
                float hz = __uint_as_float((hv[k].y & 0xFFFFu) << 16);
                float hw = __uint_as_float(hv[k].y & 0xFFFF0000u);
                ax += fmaxf(0.f, hx + fmaf(w, wv.x, bv.x));
                ay += fmaxf(0.f, hy + fmaf(w, wv.y, bv.y));
                az += fmaxf(0.f, hz + fmaf(w, wv.z, bv.z));
                aw += fmaxf(0.f, hw + fmaf(w, wv.w, bv.w));
            }
        }
    }
    u64 o = (u64)((u32)f2bf(ax) | ((u32)f2bf(ay) << 16))
          | ((u64)((u32)f2bf(az) | ((u32)f2bf(aw) << 16)) << 32);
    __builtin_nontemporal_store(o, (u64*)(aggb + (size_t)n * D + d4));
}

// ---------- MFMA GEMM: out = (relu?)((A1+A2) @ W + bias) ----------

__global__ __launch_bounds__(256) void gemm_mfma(
    const ushort* __restrict__ A1b,
    const ushort* __restrict__ A2b,   // aggb (streamed, read-once)
    const ushort* __restrict__ Wtb,
    const float*  __restrict__ bias,
    float*        __restrict__ outf,   // layer 2 (or null)
    ushort*       __restrict__ outb,   // layer 1 (or null)
    int relu)
{
    __shared__ ushort As[GR * 140];
    __shared__ ushort Ws[D * 140];

    const int t    = threadIdx.x;
    const int row0 = blockIdx.x * GR;

    for (int c = t; c < GR * (D / 4); c += 256) {
        int r  = c >> 5;
        int k4 = (c & 31) << 2;
        int row = row0 + r;
        uint2 o = make_uint2(0u, 0u);
        if (row < NN) {
            uint2 u1 = *(const uint2*)(A1b + (size_t)row * D + k4);
            u64 uu = __builtin_nontemporal_load((const u64*)(A2b + (size_t)row * D + k4));
            uint2 u2 = make_uint2((u32)uu, (u32)(uu >> 32));
            float s0 = __uint_as_float((u1.x & 0xFFFFu) << 16) + __uint_as_float((u2.x & 0xFFFFu) << 16);
            float s1 = __uint_as_float(u1.x & 0xFFFF0000u)     + __uint_as_float(u2.x & 0xFFFF0000u);
            float s2 = __uint_as_float((u1.y & 0xFFFFu) << 16) + __uint_as_float((u2.y & 0xFFFFu) << 16);
            float s3 = __uint_as_float(u1.y & 0xFFFF0000u)     + __uint_as_float(u2.y & 0xFFFF0000u);
            o.x = (u32)f2bf(s0) | ((u32)f2bf(s1) << 16);
            o.y = (u32)f2bf(s2) | ((u32)f2bf(s3) << 16);
        }
        *(uint2*)&As[r * 140 + k4] = o;
    }
    for (int c = t; c < D * (D / 4); c += 256) {
        int r  = c >> 5;
        int k4 = (c & 31) << 2;
        *(uint2*)&Ws[r * 140 + k4] = *(const uint2*)(Wtb + r * D + k4);
    }
    __syncthreads();

    const int wave = t >> 6;
    const int lane = t & 63;
    const int q    = lane >> 4;
    const int m    = lane & 15;
    const int wr   = (wave >> 1) * 32;
    const int wc   = (wave & 1) * 64;

    f32x4 acc[2][4] = {};
    #pragma unroll
    for (int kb = 0; kb < 4; ++kb) {
        int ak = kb * 32 + q * 8;
        short8 af[2];
        #pragma unroll
        for (int rg = 0; rg < 2; ++rg)
            af[rg] = *(const short8*)&As[(wr + rg * 16 + m) * 140 + ak];
        #pragma unroll
        for (int ct = 0; ct < 4; ++ct) {
            short8 bf = *(const short8*)&Ws[(wc + ct * 16 + m) * 140 + ak];
            #pragma unroll
            for (int rg = 0; rg < 2; ++rg)
                acc[rg][ct] = __builtin_amdgcn_mfma_f32_16x16x32_bf16(
                    af[rg], bf, acc[rg][ct], 0, 0, 0);
        }
    }

    #pragma unroll
    for (int ct = 0; ct < 4; ++ct) {
        int col = wc + ct * 16 + m;
        float bc = bias[col];
        #pragma unroll
        for (int rg = 0; rg < 2; ++rg) {
            #pragma unroll
            for (int r = 0; r < 4; ++r) {
                int grow = row0 + wr + rg * 16 + q * 4 + r;
                if (grow < NN) {
                    float v = acc[rg][ct][r] + bc;
                    if (relu) v = fmaxf(0.f, v);
                    if (outb) outb[(size_t)grow * D + col] = f2bf(v);
                    else __builtin_nontemporal_store(v, outf + (size_t)grow * D + col);
                }
            }
        }
    }
}

extern "C" void kernel_launch(void* const* d_in, const int* in_sizes, int n_in,
                              void* d_out, int out_size, void* d_ws, size_t ws_size,
                              hipStream_t stream)
{
    const float* x   = (const float*)d_in[0];
    const int*   ei  = (const int*)  d_in[1];
    const float* ew  = (const float*)d_in[2];
    const float* We1 = (const float*)d_in[3];
    const float* be1 = (const float*)d_in[4];
    const float* W1  = (const float*)d_in[5];
    const float* b1  = (const float*)d_in[6];
    const float* We2 = (const float*)d_in[7];
    const float* be2 = (const float*)d_in[8];
    const float* W2  = (const float*)d_in[9];
    const float* b2  = (const float*)d_in[10];

    float* out = (float*)d_out;

    // workspace (~46 MB)
    ushort* xb   = (ushort*)d_ws;                    // NN*D bf16
    ushort* hb   = xb + (size_t)NN * D;              // NN*D
    ushort* aggb = hb + (size_t)NN * D;              // NN*D
    ushort* Wt1  = aggb + (size_t)NN * D;            // 16384
    ushort* Wt2  = Wt1 + D * D;                      // 16384
    u64*   stage = (u64*)(Wt2 + D * D);              // NE u64
    int*   G     = (int*)(stage + NE);               // NC*NB
    int*   O     = G + NC * NB;                      // NC*NB
    int*   S     = O + NC * NB;                      // NB
    int*   B     = S + NB;                           // NB+1
    int*   off   = B + NB + 1;                       // NN+1

    const int* src = ei;
    const int* dst = ei + NE;

    dim3 agrid((NN * 32 + 255) / 256);               // 6250

    // ---- prep (cast x, transpose W) + hist, one launch ----
    prep_hist<<<CBLK + 8 + NC, 256, 0, stream>>>(x, xb, W1, W2, Wt1, Wt2,
                                                 dst, G);

    // ---- bucket-sorted CSR build ----
    colscan<<<(NB + 255) / 256, 256, 0, stream>>>(G, O, S);
    scanS<<<1, 1024, 0, stream>>>(S, B);
    bucket_scatter<<<NC, 256, 0, stream>>>(src, dst, ew, O, B, stage);
    bucket_csr<<<NB, 256, 0, stream>>>(B, stage, off);

    // ---- layer 1 ----
    aggregate<<<agrid, 256, 0, stream>>>(xb, off, stage, We1, be1, aggb);
    gemm_mfma<<<GG, 256, 0, stream>>>(xb, aggb, Wt1, b1, nullptr, hb, 1);

    // ---- layer 2 ----
    aggregate<<<agrid, 256, 0, stream>>>(hb, off, stage, We2, be2, aggb);
    gemm_mfma<<<GG, 256, 0, stream>>>(hb, aggb, Wt2, b2, out, nullptr, 0);
}